// Round 11
// baseline (131.602 us; speedup 1.0000x reference)
//
#include <hip/hip_runtime.h>

typedef float f32x4 __attribute__((ext_vector_type(4)));
typedef _Float16 h8 __attribute__((ext_vector_type(8)));
typedef unsigned short us8 __attribute__((ext_vector_type(8)));
typedef unsigned short us4 __attribute__((ext_vector_type(4)));

#define DEV __device__ __forceinline__
#define SBARRIER() asm volatile("s_barrier" ::: "memory")
#define LGKM0()    asm volatile("s_waitcnt lgkmcnt(0)" ::: "memory")
#define SCHED0()   __builtin_amdgcn_sched_barrier(0)

constexpr int Bb = 32, Nn = 1024, Mm = 576, Dd = 768;
constexpr float L2E = 1.44269504088896340736f;

// ws layout (ushort elems), fragment-major for 16x16x32 f16 MFMA:
//   Kf: [b][kvtile 36][dc 24][lane 64][8]   B-frag: K[kvt*16+(l&15)][dc*32+(l>>4)*8+j]
//   Vf: [b][kc 18][dtile 48][lane 64][8]    B-frag: V[kc*32+(l>>4)*8+j][dt*16+(l&15)]
constexpr size_t KF_ELEMS = (size_t)Bb * 36 * 24 * 512;  // 14,155,776

DEV unsigned short f2h(float x) {
  _Float16 h = (_Float16)x;
  return __builtin_bit_cast(unsigned short, h);
}
DEV void gll16(const void* g, void* l) {
  __builtin_amdgcn_global_load_lds(
      (const __attribute__((address_space(1))) void*)g,
      (__attribute__((address_space(3))) void*)l, 16, 0, 0);
}

// ---------------- pre-pass: K -> Kf, Vf (fragment-major f16) — unchanged
__global__ __launch_bounds__(256)
void fusion_prep(const float* __restrict__ K, unsigned short* __restrict__ Kf,
                 unsigned short* __restrict__ Vf)
{
  const int t = threadIdx.x;
  const int b = blockIdx.x / 24, dc = blockIdx.x % 24;
  const int l = t & 63;
  {
    const int lt = t >> 6;
    const int ro = l & 15, go = l >> 4;
#pragma unroll
    for (int it = 0; it < 9; ++it) {
      const int kvt = it * 4 + lt;
      const float* src = K + ((size_t)(b * Mm + kvt * 16 + ro)) * Dd + dc * 32 + go * 8;
      f32x4 v0 = *(const f32x4*)src;
      f32x4 v1 = *(const f32x4*)(src + 4);
      us8 h;
      h[0]=f2h(v0[0]); h[1]=f2h(v0[1]); h[2]=f2h(v0[2]); h[3]=f2h(v0[3]);
      h[4]=f2h(v1[0]); h[5]=f2h(v1[1]); h[6]=f2h(v1[2]); h[7]=f2h(v1[3]);
      *(us8*)&Kf[(((size_t)((b * 36 + kvt) * 24 + dc)) << 9) + l * 8] = h;
    }
  }
  {
    const int kch = t >> 7;
    const int dtl = (t >> 6) & 1;
    const int d = dc * 32 + dtl * 16 + (l & 15);
    const int kvo = (l >> 4) * 8;
#pragma unroll
    for (int it = 0; it < 9; ++it) {
      const int kc = it * 2 + kch;
      const int kv0 = kc * 32 + kvo;
      us8 o;
#pragma unroll
      for (int j = 0; j < 8; ++j)
        o[j] = f2h(K[((size_t)(b * Mm + kv0 + j)) * Dd + d]);
      *(us8*)&Vf[(((size_t)((b * 18 + kc) * 48 + dc * 2 + dtl)) << 9) + l * 8] = o;
    }
  }
}

// ---------------- main: 64q/512thr blocks, LDS=81920B exactly -> 2 blocks/CU.
// LDS map (bytes): bufK[2] @ {0, 36864}; Qbuf (single) @ 73728, 8192 B,
//   layout [qtile4][hl2][lane64][16B]. Post-QK: sP (64x576 f16, pitch 1152,
//   XOR swizzle) aliases 0..73728; sRa @73728, sRb @74752 alias dead Qbuf.
__global__ __launch_bounds__(512, 4)
void fusion_main(const float* __restrict__ Q, const unsigned short* __restrict__ Kf,
                 const unsigned short* __restrict__ Vf, float* __restrict__ Out)
{
  __shared__ alignas(16) unsigned char lds[81920];

  const int tid  = threadIdx.x;
  const int lane = tid & 63;
  const int w    = tid >> 6;      // 0..7
  const int g    = lane >> 4;
  const int ln   = lane & 15;
  const int wq   = w >> 2;        // QK: 0..1, q rows [wq*32,+32)
  const int wkv  = w & 3;         // QK: kv slice [wkv*144,+144)

  // XCD swizzle: all 16 q-tiles of a batch on one XCD
  const int bid = blockIdx.x;
  const int xcd = bid & 7, ii = bid >> 3;
  const int b  = (xcd << 2) | (ii >> 4);
  const int q0 = (ii & 15) * 64;

  const float* Qb = Q + ((size_t)(b * Nn + q0)) * Dd;
  const unsigned char* KfB = (const unsigned char*)Kf + ((size_t)(b * 36 * 24) << 10);
  const unsigned short* VfB = Vf + ((size_t)(b * 18 * 48) << 9);

  // K staging split: 36 units over 8 waves (w<4: 5 units, w>=4: 4 units)
  const int nu = (w < 4) ? 5 : 4;
  const int u0 = (w < 4) ? w * 5 : 20 + (w - 4) * 4;

  // Q staging: thread -> (row, 4-col group); frag layout addresses
  const int qrow = tid >> 3;             // 0..63
  const int qcg  = tid & 7;              // cols qcg*4..+3 of the 32-chunk
  const float* qsrc = Qb + (size_t)qrow * Dd + qcg * 4;
  unsigned char* qdst = lds + 73728 + (qrow >> 4) * 2048
                        + ((qcg >> 1) * 16 + (qrow & 15)) * 16 + (qcg & 1) * 8;

  float* sRa = (float*)(lds + 73728);    // [4][64] — aliases Qbuf post-QK
  float* sRb = (float*)(lds + 74752);

  // ---------------- prologue: K(0) -> bufK[0]; Q(0) -> Qbuf
  {
    f32x4 qv = *(const f32x4*)qsrc;
#pragma unroll
    for (int j = 0; j < 5; ++j)
      if (j < nu)
        gll16(KfB + ((size_t)((u0 + j) * 24) << 10) + (lane << 4), lds + (u0 + j) * 1024);
    us4 hv, lv;
#pragma unroll
    for (int k = 0; k < 4; ++k) {
      float x = qv[k] * L2E; _Float16 hh = (_Float16)x;
      hv[k] = __builtin_bit_cast(unsigned short, hh);
      lv[k] = __builtin_bit_cast(unsigned short, (_Float16)(x - (float)hh));
    }
    *(us4*)qdst = hv;
    *(us4*)(qdst + 1024) = lv;
    __syncthreads();
  }

  // ---------------- QK: acc[mt 2][nt 9] = [32 q][144 kv]
  f32x4 acc[2][9];
#pragma unroll
  for (int mt = 0; mt < 2; ++mt)
#pragma unroll
    for (int nt = 0; nt < 9; ++nt) acc[mt][nt] = (f32x4){0.f, 0.f, 0.f, 0.f};

#pragma unroll 1
  for (int c = 0; c < 24; ++c) {
    const int cur = c & 1, nxt = cur ^ 1;
    const bool stg = (c < 23);
    // [A] read Q(c) frags from single Qbuf, then cheap barrier (no vmem drain)
    h8 qh[2], ql[2];
#pragma unroll
    for (int mt = 0; mt < 2; ++mt) {
      const unsigned char* qb = lds + 73728 + (wq * 2 + mt) * 2048;
      qh[mt] = *(const h8*)(qb + lane * 16);
      ql[mt] = *(const h8*)(qb + 1024 + lane * 16);
    }
    LGKM0();
    SBARRIER();
    SCHED0();
    // [B] stage next chunk + compute current
    f32x4 qv;
    if (stg) qv = *(const f32x4*)(qsrc + (c + 1) * 32);  // issued FIRST (oldest vmem)
    SCHED0();
    if (stg) {
#pragma unroll
      for (int j = 0; j < 5; ++j)
        if (j < nu)
          gll16(KfB + ((size_t)((u0 + j) * 24 + c + 1) << 10) + (lane << 4),
                lds + nxt * 36864 + (u0 + j) * 1024);
    }
    // MFMA stream: K frags ds_read inline (compiler interleaves, counted lgkm)
    const unsigned char* kb = lds + cur * 36864;
#pragma unroll
    for (int nt = 0; nt < 9; ++nt) {
      const h8 kf = *(const h8*)(kb + (wkv * 9 + nt) * 1024 + lane * 16);
#pragma unroll
      for (int mt = 0; mt < 2; ++mt) {
        acc[mt][nt] = __builtin_amdgcn_mfma_f32_16x16x32_f16(qh[mt], kf, acc[mt][nt], 0, 0, 0);
        acc[mt][nt] = __builtin_amdgcn_mfma_f32_16x16x32_f16(ql[mt], kf, acc[mt][nt], 0, 0, 0);
      }
    }
    if (stg) {  // convert + write Q(c+1) into Qbuf (safe: bar1 passed, readers done)
      us4 hv, lv;
#pragma unroll
      for (int k = 0; k < 4; ++k) {
        float x = qv[k] * L2E; _Float16 hh = (_Float16)x;
        hv[k] = __builtin_bit_cast(unsigned short, hh);
        lv[k] = __builtin_bit_cast(unsigned short, (_Float16)(x - (float)hh));
      }
      *(us4*)qdst = hv;
      *(us4*)(qdst + 1024) = lv;
    }
    __syncthreads();   // bar2: K(c+1) gll16 + Q ds_writes drained
  }

  // ---------------- one-shot softmax (exp2 domain; Q pre-scaled by log2 e)
  float pm[2][4];
#pragma unroll
  for (int mt = 0; mt < 2; ++mt)
#pragma unroll
    for (int i2 = 0; i2 < 4; ++i2) {
      float v = acc[mt][0][i2];
#pragma unroll
      for (int nt = 1; nt < 9; ++nt) v = fmaxf(v, acc[mt][nt][i2]);
      pm[mt][i2] = v;
    }
#pragma unroll
  for (int mk = 1; mk < 16; mk <<= 1)
#pragma unroll
    for (int mt = 0; mt < 2; ++mt)
#pragma unroll
      for (int i2 = 0; i2 < 4; ++i2)
        pm[mt][i2] = fmaxf(pm[mt][i2], __shfl_xor(pm[mt][i2], mk, 64));
  if (ln == 0) {
#pragma unroll
    for (int mt = 0; mt < 2; ++mt)
#pragma unroll
      for (int i2 = 0; i2 < 4; ++i2)
        sRa[wkv * 64 + wq * 32 + mt * 16 + g * 4 + i2] = pm[mt][i2];
  }
  __syncthreads();

  float mfin[2][4], ps[2][4];
#pragma unroll
  for (int mt = 0; mt < 2; ++mt)
#pragma unroll
    for (int i2 = 0; i2 < 4; ++i2) {
      const int rw = wq * 32 + mt * 16 + g * 4 + i2;
      mfin[mt][i2] = fmaxf(fmaxf(sRa[rw], sRa[64 + rw]), fmaxf(sRa[128 + rw], sRa[192 + rw]));
      ps[mt][i2] = 0.f;
    }
#pragma unroll
  for (int mt = 0; mt < 2; ++mt)
#pragma unroll
    for (int nt = 0; nt < 9; ++nt)
#pragma unroll
      for (int i2 = 0; i2 < 4; ++i2) {
        const float p = exp2f(acc[mt][nt][i2] - mfin[mt][i2]);
        acc[mt][nt][i2] = p;
        ps[mt][i2] += p;
      }
#pragma unroll
  for (int mk = 1; mk < 16; mk <<= 1)
#pragma unroll
    for (int mt = 0; mt < 2; ++mt)
#pragma unroll
      for (int i2 = 0; i2 < 4; ++i2)
        ps[mt][i2] += __shfl_xor(ps[mt][i2], mk, 64);
  if (ln == 0) {
#pragma unroll
    for (int mt = 0; mt < 2; ++mt)
#pragma unroll
      for (int i2 = 0; i2 < 4; ++i2)
        sRb[wkv * 64 + wq * 32 + mt * 16 + g * 4 + i2] = ps[mt][i2];
  }
  __syncthreads();

  // normalize P -> swizzled sP (aliases dead bufK)
  {
    unsigned short* sPp = (unsigned short*)lds;
#pragma unroll
    for (int mt = 0; mt < 2; ++mt)
#pragma unroll
      for (int i2 = 0; i2 < 4; ++i2) {
        const int rw = wq * 32 + mt * 16 + g * 4 + i2;
        const float inv = 1.0f / ((sRb[rw] + sRb[64 + rw]) + (sRb[128 + rw] + sRb[192 + rw]));
#pragma unroll
        for (int nt = 0; nt < 9; ++nt) {
          const int u = wkv * 18 + nt * 2 + (ln >> 3);
          sPp[rw * 576 + ((u ^ (rw & 7)) << 3) + (ln & 7)] = f2h(acc[mt][nt][i2] * inv);
        }
      }
  }
  __syncthreads();

  // ---------------- PV: per wave [64q x 48d] x 2 passes; V frags direct from global
#pragma unroll 1
  for (int p = 0; p < 2; ++p) {
    f32x4 O[4][3];
#pragma unroll
    for (int mt = 0; mt < 4; ++mt)
#pragma unroll
      for (int nt = 0; nt < 3; ++nt) O[mt][nt] = (f32x4){0.f, 0.f, 0.f, 0.f};

#pragma unroll 1
    for (int kc = 0; kc < 18; ++kc) {
      h8 vf[3];
#pragma unroll
      for (int nt = 0; nt < 3; ++nt)
        vf[nt] = *(const h8*)(VfB + (((size_t)(kc * 48 + w * 6 + p * 3 + nt)) << 9) + lane * 8);
      h8 pa[4];
#pragma unroll
      for (int mt = 0; mt < 4; ++mt) {
        const int row = mt * 16 + ln;
        const int u = kc * 4 + g;
        pa[mt] = *(const h8*)(lds + row * 1152 + ((u ^ (row & 7)) << 4));
      }
#pragma unroll
      for (int nt = 0; nt < 3; ++nt)
#pragma unroll
        for (int mt = 0; mt < 4; ++mt)
          O[mt][nt] = __builtin_amdgcn_mfma_f32_16x16x32_f16(pa[mt], vf[nt], O[mt][nt], 0, 0, 0);
    }

    float* ob = Out + ((size_t)(b * Nn + q0)) * Dd;
#pragma unroll
    for (int mt = 0; mt < 4; ++mt)
#pragma unroll
      for (int nt = 0; nt < 3; ++nt)
#pragma unroll
        for (int i2 = 0; i2 < 4; ++i2)
          ob[(size_t)(mt * 16 + g * 4 + i2) * Dd + w * 96 + p * 48 + nt * 16 + ln] = O[mt][nt][i2];
  }
}

extern "C" void kernel_launch(void* const* d_in, const int* in_sizes, int n_in,
                              void* d_out, int out_size, void* d_ws, size_t ws_size,
                              hipStream_t stream) {
  const float* Q = (const float*)d_in[0];
  const float* K = (const float*)d_in[1];
  float* Out = (float*)d_out;
  unsigned short* Kf = (unsigned short*)d_ws;
  unsigned short* Vf = Kf + KF_ELEMS;
  fusion_prep<<<dim3(Bb * 24), dim3(256), 0, stream>>>(K, Kf, Vf);
  fusion_main<<<dim3(Bb * 16), dim3(512), 0, stream>>>(Q, Kf, Vf, Out);
}